// Round 1
// baseline (26.748 us; speedup 1.0000x reference)
//
#include <hip/hip_runtime.h>
#include <math.h>

#define BB 32
#define MM 256
#define H2 32
#define NOUT 8

__global__ __launch_bounds__(256) void interaction_kernel(
    const float* __restrict__ x, const int* __restrict__ mask,
    const float* __restrict__ W1, const float* __restrict__ b1,
    const float* __restrict__ W2, const float* __restrict__ b2,
    float* __restrict__ out)
{
    const int bi = blockIdx.x;      // 0 .. B*M-1
    const int b  = bi >> 8;         // / 256
    const int i  = bi & 255;
    const int j  = threadIdx.x;

    // out[(b*NOUT + p)*M*M + i*M + j]
    const size_t obase = ((size_t)b * NOUT) * (MM * MM) + (size_t)i * MM + j;

    const int mi = mask[b * MM + i];
    if (mi == 0) {
        #pragma unroll
        for (int p = 0; p < NOUT; ++p) out[obase + (size_t)p * (MM * MM)] = 0.f;
        return;
    }

    const int mj = mask[b * MM + j];
    if (mj == 0) {
        #pragma unroll
        for (int p = 0; p < NOUT; ++p) out[obase + (size_t)p * (MM * MM)] = 0.f;
        return;
    }

    // point data: i is block-uniform (scalar loads), j is per-thread
    const float eta_i = x[(b * MM + i) * 3 + 0];
    const float phi_i = x[(b * MM + i) * 3 + 1];
    const float lpt_i = x[(b * MM + i) * 3 + 2];
    const float eta_j = x[(b * MM + j) * 3 + 0];
    const float phi_j = x[(b * MM + j) * 3 + 1];
    const float lpt_j = x[(b * MM + j) * 3 + 2];

    const float ept_i = expf(lpt_i);
    const float ept_j = expf(lpt_j);

    const float d_eta = eta_i - eta_j;
    const float d_phi = phi_i - phi_j;
    const float dr2   = d_eta * d_eta + d_phi * d_phi;

    // feat order in reference: [mass_log, dr_log, kt_log]
    const float dr_log = (dr2 > 0.f) ? 0.5f * logf(dr2) : 0.f;

    const float kt     = fminf(ept_i, ept_j) * sqrtf(dr2);
    const float kt_log = (kt > 0.f) ? logf(kt) : 0.f;

    // mimic reference operand order exactly: 2*ei*ej*(cosh - cos)
    const float m2       = 2.0f * ept_i * ept_j * (coshf(d_eta) - cosf(d_phi));
    const float mass_log = (m2 > 0.f) ? logf(m2) : 0.f;

    float o[NOUT];
    #pragma unroll
    for (int p = 0; p < NOUT; ++p) o[p] = b2[p];

    #pragma unroll
    for (int k = 0; k < H2; ++k) {
        float z = b1[k];
        z = fmaf(mass_log, W1[k * 3 + 0], z);
        z = fmaf(dr_log,   W1[k * 3 + 1], z);
        z = fmaf(kt_log,   W1[k * 3 + 2], z);
        z = (z >= 0.f) ? z : 0.01f * z;   // leaky_relu, slope 0.01
        #pragma unroll
        for (int p = 0; p < NOUT; ++p)
            o[p] = fmaf(z, W2[p * H2 + k], o[p]);
    }

    #pragma unroll
    for (int p = 0; p < NOUT; ++p)
        out[obase + (size_t)p * (MM * MM)] = o[p];
}

extern "C" void kernel_launch(void* const* d_in, const int* in_sizes, int n_in,
                              void* d_out, int out_size, void* d_ws, size_t ws_size,
                              hipStream_t stream) {
    const float* x    = (const float*)d_in[0];
    const int*   mask = (const int*)d_in[1];
    const float* W1   = (const float*)d_in[2];
    const float* b1   = (const float*)d_in[3];
    const float* W2   = (const float*)d_in[4];
    const float* b2   = (const float*)d_in[5];
    float* out = (float*)d_out;

    dim3 grid(BB * MM);
    dim3 block(MM);
    interaction_kernel<<<grid, block, 0, stream>>>(x, mask, W1, b1, W2, b2, out);
}